// Round 1
// baseline (1278.804 us; speedup 1.0000x reference)
//
#include <hip/hip_runtime.h>

// Ocean advection + 3x3 binomial smoothing, 48 steps, fp32.
//
// Round-N: TEMPORAL FUSION x2. Each kernel performs TWO advect+smooth steps,
// keeping the intermediate field entirely in registers. Unique memory traffic
// per simulated step halves (ug/vg/mask/T read once per 2 steps).
//
// fused2_kernel structure:
//   - one 256-thread block (4 waves) spans the FULL width W=1024
//     (wave wv owns cols [wv*256, wv*256+256), one float4 per lane)
//   - block streams down a 16-row chunk; 4-stage register pipeline skewed
//     2 rows/stage:   A1 = advect(T), S1 = smooth(A1), A2 = advect(S1),
//     out = smooth(A2).
//   - x-neighbors inside a wave via __shfl; across wave boundaries via tiny
//     LDS "edge rings" (8-row ring x 4 waves x {first,last} col). The 2-row
//     skew makes every cross-wave edge read >=1 barrier old -> ONE
//     __syncthreads per row, race-free (slot distances 1..3 mod 8).
//   - all 9 global loads per row prefetched one iteration ahead.

#define DEG2RAD 0.017453292519943295f
#define R_EARTH 6371000.0f
#define DT_S 600.0f

constexpr int NT    = 256;   // threads per block
constexpr int STRIP = 8;     // legacy stream kernel: rows per wave
constexpr int WPW   = 256;   // legacy stream kernel: cols per wave

__global__ __launch_bounds__(256)
void prep_kernel(const float* __restrict__ lat, const float* __restrict__ lon,
                 float* __restrict__ coef, int H) {
    int h = blockIdx.x * blockDim.x + threadIdx.x;
    if (h < H) {
        float dlon = lon[1] - lon[0];
        coef[h] = 1.0f / (R_EARTH * DEG2RAD * dlon * cosf(lat[h] * DEG2RAD));
    }
    if (h == 0) {
        float dlat = lat[1] - lat[0];
        coef[H] = 1.0f / (R_EARTH * DEG2RAD * dlat);
    }
}

// ------------------------- fused 2-step kernel -----------------------------
constexpr int FWAVES = 4;    // waves per block, FWAVES*256 must == W
constexpr int SH2    = 16;   // output rows per block chunk

__global__ __launch_bounds__(256, 2)
void fused2_kernel(const float* __restrict__ Tin, const float* __restrict__ ug,
                   const float* __restrict__ vg, const float* __restrict__ mask,
                   const float* __restrict__ coef, float* __restrict__ Tout,
                   int H, int W) {
    const int lane = threadIdx.x & 63;
    const int wv   = threadIdx.x >> 6;
    const int h0   = blockIdx.x * SH2;
    const int b    = blockIdx.y;
    const int gw   = (wv << 8) + (lane << 2);
    const size_t plane = (size_t)H * W;
    const float* __restrict__ Tb  = Tin + b * plane;
    const float* __restrict__ ugb = ug  + b * plane;
    const float* __restrict__ vgb = vg  + b * plane;
    float* __restrict__ To = Tout + b * plane;
    const float inv_dy = coef[H];
    const bool isL = (lane == 0), isR = (lane == 63);
    const bool domL = (wv == 0), domR = (wv == FWAVES - 1);

    // edge rings: [row & 7][wave][0 = value at first col, 1 = value at last col]
    __shared__ float eT [8][FWAVES][2];
    __shared__ float eA1[8][FWAVES][2];
    __shared__ float eS1[8][FWAVES][2];
    __shared__ float eA2[8][FWAVES][2];

    auto rowc = [&](int r) { return min(max(r, 0), H - 1); };
    auto ld4 = [&](const float* __restrict__ p, int r) -> float4 {
        return *(const float4*)(p + (size_t)rowc(r) * W + gw);
    };

    const float4 z4 = make_float4(0.f, 0.f, 0.f, 0.f);
    // T chain: during body of iter j (tau = h0-4+j): t0..t2 = rows tau-3..tau-1
    float4 t0 = z4, t1 = z4, t2 = z4, t3 = z4;
    // stage output chains: during body = rows (stage_row-1 .. stage_row+1)
    float4 a1p = z4, a1c = z4, a1n = z4;     // A1 rows s-1, s, s+1  (s = tau-4)
    float4 s1p = z4, s1c = z4, s1n = z4;     // S1 rows q-1, q, q+1  (q = tau-6)
    float4 a2p = z4, a2c = z4, a2n = z4;     // A2 rows r-1, r, r+1  (r = tau-8)
    // one-iteration-ahead prefetch registers
    float4 uA_pf = z4, gA_pf = z4, mA_pf = z4;   // rows a+1 (A1 inputs)
    float4 uQ_pf = z4, gQ_pf = z4, mQ_pf = z4;   // rows q+1 (A2 inputs)
    float4 mS_pf = z4, mR_pf = z4;               // mask rows s+1, r+1

    #pragma unroll 4
    for (int j = 0; j < SH2 + 12; ++j) {
        const int tau = h0 - 4 + j;
        const int a = tau - 2, s = tau - 4, q = tau - 6, r = tau - 8;

        // ---- consume prefetches, roll T, issue next-iteration loads ----
        float4 uA = uA_pf, gA = gA_pf, mA = mA_pf;
        float4 uQ = uQ_pf, gQ = gQ_pf, mQ = mQ_pf;
        float4 mS = mS_pf, mR = mR_pf;
        t0 = t1; t1 = t2; t2 = t3;
        t3 = ld4(Tb, tau);
        uA_pf = ld4(ugb, a + 1); gA_pf = ld4(vgb, a + 1); mA_pf = ld4(mask, a + 1);
        uQ_pf = ld4(ugb, q + 1); gQ_pf = ld4(vgb, q + 1); mQ_pf = ld4(mask, q + 1);
        mS_pf = ld4(mask, s + 1); mR_pf = ld4(mask, r + 1);

        // publish T edges (row tau-1 = t2, loaded last iteration)
        if (isL) eT[(tau - 1) & 7][wv][0] = t2.x;
        if (isR) eT[(tau - 1) & 7][wv][1] = t2.w;

        // ---------------- stage A1: advect T, row a = tau-2 ----------------
        float4 a1_new = z4;
        if (a >= h0 - 3 && a <= h0 + SH2 + 2) {
            if (a >= 0 && a < H) {
                const float ix  = coef[a];
                const float sy  = (a == 0 || a == H - 1) ? inv_dy : 0.5f * inv_dy;
                const float sxh = 0.5f * ix;
                float cL = __shfl_up(t1.w, 1);
                float cR = __shfl_down(t1.x, 1);
                float sxx = sxh, sxw = sxh;
                if (isL) { if (domL) { cL = t1.x; sxx = ix; } else cL = eT[a & 7][wv - 1][1]; }
                if (isR) { if (domR) { cR = t1.w; sxw = ix; } else cR = eT[a & 7][wv + 1][0]; }
                a1_new.x = t1.x + DT_S * (-(uA.x * ((t1.y - cL) * sxx) + gA.x * ((t2.x - t0.x) * sy)) * mA.x);
                a1_new.y = t1.y + DT_S * (-(uA.y * ((t1.z - t1.x) * sxh) + gA.y * ((t2.y - t0.y) * sy)) * mA.y);
                a1_new.z = t1.z + DT_S * (-(uA.z * ((t1.w - t1.y) * sxh) + gA.z * ((t2.z - t0.z) * sy)) * mA.z);
                a1_new.w = t1.w + DT_S * (-(uA.w * ((cR - t1.z) * sxw) + gA.w * ((t2.w - t0.w) * sy)) * mA.w);
            }
            if (isL) eA1[a & 7][wv][0] = a1_new.x;
            if (isR) eA1[a & 7][wv][1] = a1_new.w;
        }

        // ---------------- stage S1: smooth A1, row s = tau-4 ----------------
        float4 s1_new = z4;
        if (s >= h0 - 2 && s <= h0 + SH2 + 1) {
            if (s >= 0 && s < H) {
                float4 v;
                v.x = a1p.x + 2.f * a1c.x + a1n.x;
                v.y = a1p.y + 2.f * a1c.y + a1n.y;
                v.z = a1p.z + 2.f * a1c.z + a1n.z;
                v.w = a1p.w + 2.f * a1c.w + a1n.w;
                float vL = __shfl_up(v.w, 1);
                float vR = __shfl_down(v.x, 1);
                if (isL) vL = domL ? 0.f
                    : (eA1[(s - 1) & 7][wv - 1][1] + 2.f * eA1[s & 7][wv - 1][1] + eA1[(s + 1) & 7][wv - 1][1]);
                if (isR) vR = domR ? 0.f
                    : (eA1[(s - 1) & 7][wv + 1][0] + 2.f * eA1[s & 7][wv + 1][0] + eA1[(s + 1) & 7][wv + 1][0]);
                s1_new.x = (vL  + 2.f * v.x + v.y) * 0.0625f * mS.x;
                s1_new.y = (v.x + 2.f * v.y + v.z) * 0.0625f * mS.y;
                s1_new.z = (v.y + 2.f * v.z + v.w) * 0.0625f * mS.z;
                s1_new.w = (v.z + 2.f * v.w + vR ) * 0.0625f * mS.w;
            }
            if (isL) eS1[s & 7][wv][0] = s1_new.x;
            if (isR) eS1[s & 7][wv][1] = s1_new.w;
        }

        // ---------------- stage A2: advect S1, row q = tau-6 ----------------
        float4 a2_new = z4;
        if (q >= h0 - 1 && q <= h0 + SH2) {
            if (q >= 0 && q < H) {
                const float ix  = coef[q];
                const float sxh = 0.5f * ix;
                float cL = __shfl_up(s1c.w, 1);
                float cR = __shfl_down(s1c.x, 1);
                float sxx = sxh, sxw = sxh;
                if (isL) { if (domL) { cL = s1c.x; sxx = ix; } else cL = eS1[q & 7][wv - 1][1]; }
                if (isR) { if (domR) { cR = s1c.w; sxw = ix; } else cR = eS1[q & 7][wv + 1][0]; }
                // y-derivative: one-sided at domain rows 0 / H-1 (S1 chain has
                // zeros outside the domain, so select operands explicitly)
                const float4 yl = (q == 0)     ? s1c : s1p;
                const float4 yh = (q == H - 1) ? s1c : s1n;
                const float sy  = (q == 0 || q == H - 1) ? inv_dy : 0.5f * inv_dy;
                a2_new.x = s1c.x + DT_S * (-(uQ.x * ((s1c.y - cL) * sxx) + gQ.x * ((yh.x - yl.x) * sy)) * mQ.x);
                a2_new.y = s1c.y + DT_S * (-(uQ.y * ((s1c.z - s1c.x) * sxh) + gQ.y * ((yh.y - yl.y) * sy)) * mQ.y);
                a2_new.z = s1c.z + DT_S * (-(uQ.z * ((s1c.w - s1c.y) * sxh) + gQ.z * ((yh.z - yl.z) * sy)) * mQ.z);
                a2_new.w = s1c.w + DT_S * (-(uQ.w * ((cR - s1c.z) * sxw) + gQ.w * ((yh.w - yl.w) * sy)) * mQ.w);
            }
            if (isL) eA2[q & 7][wv][0] = a2_new.x;
            if (isR) eA2[q & 7][wv][1] = a2_new.w;
        }

        // ---------------- stage out: smooth A2, row r = tau-8 ---------------
        if (r >= h0 && r < min(h0 + SH2, H)) {
            float4 v;
            v.x = a2p.x + 2.f * a2c.x + a2n.x;
            v.y = a2p.y + 2.f * a2c.y + a2n.y;
            v.z = a2p.z + 2.f * a2c.z + a2n.z;
            v.w = a2p.w + 2.f * a2c.w + a2n.w;
            float vL = __shfl_up(v.w, 1);
            float vR = __shfl_down(v.x, 1);
            if (isL) vL = domL ? 0.f
                : (eA2[(r - 1) & 7][wv - 1][1] + 2.f * eA2[r & 7][wv - 1][1] + eA2[(r + 1) & 7][wv - 1][1]);
            if (isR) vR = domR ? 0.f
                : (eA2[(r - 1) & 7][wv + 1][0] + 2.f * eA2[r & 7][wv + 1][0] + eA2[(r + 1) & 7][wv + 1][0]);
            float4 o;
            o.x = (vL  + 2.f * v.x + v.y) * 0.0625f * mR.x;
            o.y = (v.x + 2.f * v.y + v.z) * 0.0625f * mR.y;
            o.z = (v.y + 2.f * v.z + v.w) * 0.0625f * mR.z;
            o.w = (v.z + 2.f * v.w + vR ) * 0.0625f * mR.w;
            *(float4*)(To + (size_t)r * W + gw) = o;
        }

        // ---- roll stage chains; single barrier makes this iteration's
        // ---- edge publishes visible to the next iteration ----
        a1p = a1c; a1c = a1n; a1n = a1_new;
        s1p = s1c; s1c = s1n; s1n = s1_new;
        a2p = a2c; a2c = a2n; a2n = a2_new;
        __syncthreads();
    }
}

// --------- legacy single-step stream kernel (fallback, W % 256 == 0) -------
__global__ __launch_bounds__(256, 4)
void stream_kernel(const float* __restrict__ Tin, const float* __restrict__ ug,
                   const float* __restrict__ vg, const float* __restrict__ mask,
                   const float* __restrict__ coef, float* __restrict__ Tout,
                   int H, int W) {
    const int lane = threadIdx.x & 63;
    const int wv   = threadIdx.x >> 6;
    const int ws   = blockIdx.x * WPW;
    const int hs   = (blockIdx.y * 4 + wv) * STRIP;
    const int b    = blockIdx.z;
    if (hs >= H) return;
    const size_t plane = (size_t)H * W;
    const float* __restrict__ Tb  = Tin + b * plane;
    const float* __restrict__ ugb = ug  + b * plane;
    const float* __restrict__ vgb = vg  + b * plane;
    float* __restrict__ To = Tout + b * plane;
    const float inv_dy = coef[H];
    const bool atL = (ws == 0);
    const bool atR = (ws + WPW >= W);
    const bool isL = (lane == 0);
    const bool isR = (lane == 63);
    const int gw = ws + 4 * lane;

    auto clampr = [&](int r) { return min(max(r, 0), H - 1); };
    auto ldT = [&](int r) -> float4 {
        return *(const float4*)(Tb + (size_t)clampr(r) * W + gw);
    };
    auto ldL = [&](int r) -> float2 {
        float4 q = *(const float4*)(Tb + (size_t)clampr(r) * W + (ws - 4));
        return make_float2(q.z, q.w);
    };
    auto ldR = [&](int r) -> float2 {
        float4 q = *(const float4*)(Tb + (size_t)clampr(r) * W + (ws + WPW));
        return make_float2(q.x, q.y);
    };

    float4 tp, tc, tn;
    float  tLp_w = 0.f; float2 tLc = make_float2(0.f, 0.f), tLn = make_float2(0.f, 0.f);
    float  tRp_x = 0.f; float2 tRc = make_float2(0.f, 0.f), tRn = make_float2(0.f, 0.f);

    auto roll = [&](int rnext) {
        tp = tc; tc = tn; tn = ldT(rnext);
        if (!atL) { tLp_w = tLc.y; tLc = tLn; tLn = ldL(rnext); }
        if (!atR) { tRp_x = tRc.x; tRc = tRn; tRn = ldR(rnext); }
    };

    auto advrow = [&](int r, float4& a, float& aL, float& aR, float4& mOut) {
        if (r < 0 || r >= H) {
            a = make_float4(0.f, 0.f, 0.f, 0.f); aL = 0.f; aR = 0.f;
            mOut = make_float4(0.f, 0.f, 0.f, 0.f); return;
        }
        const size_t ro = (size_t)r * W;
        const float ix  = coef[r];
        const float sy  = (r == 0 || r == H - 1) ? inv_dy : 0.5f * inv_dy;
        const float sxh = 0.5f * ix;
        float4 u4 = *(const float4*)(ugb + ro + gw);
        float4 g4 = *(const float4*)(vgb + ro + gw);
        float4 m4 = *(const float4*)(mask + ro + gw);
        float cLw = __shfl_up(tc.w, 1);
        float cRx = __shfl_down(tc.x, 1);
        float sxx = sxh, sxw = sxh;
        if (isL) { if (atL) { cLw = tc.x; sxx = ix; } else { cLw = tLc.y; } }
        if (isR) { if (atR) { cRx = tc.w; sxw = ix; } else { cRx = tRc.x; } }
        a.x = tc.x + DT_S * (-(u4.x * ((tc.y - cLw) * sxx) + g4.x * ((tn.x - tp.x) * sy)) * m4.x);
        a.y = tc.y + DT_S * (-(u4.y * ((tc.z - tc.x) * sxh) + g4.y * ((tn.y - tp.y) * sy)) * m4.y);
        a.z = tc.z + DT_S * (-(u4.z * ((tc.w - tc.y) * sxh) + g4.z * ((tn.z - tp.z) * sy)) * m4.z);
        a.w = tc.w + DT_S * (-(u4.w * ((cRx - tc.z) * sxw) + g4.w * ((tn.w - tp.w) * sy)) * m4.w);
        if (!atL) {
            float uL = ((const float4*)(ugb + ro + (ws - 4)))->w;
            float gL = ((const float4*)(vgb + ro + (ws - 4)))->w;
            float mL = ((const float4*)(mask + ro + (ws - 4)))->w;
            aL = tLc.y + DT_S * (-(uL * ((tc.x - tLc.x) * sxh) + gL * ((tLn.y - tLp_w) * sy)) * mL);
        } else aL = 0.f;
        if (!atR) {
            float uR = ((const float4*)(ugb + ro + (ws + WPW)))->x;
            float gR = ((const float4*)(vgb + ro + (ws + WPW)))->x;
            float mR = ((const float4*)(mask + ro + (ws + WPW)))->x;
            aR = tRc.x + DT_S * (-(uR * ((tRc.y - tc.w) * sxh) + gR * ((tRn.x - tRp_x) * sy)) * mR);
        } else aR = 0.f;
        mOut = m4;
    };

    tp = ldT(hs - 2); tc = ldT(hs - 1); tn = ldT(hs);
    if (!atL) { float2 q = ldL(hs - 2); tLp_w = q.y; tLc = ldL(hs - 1); tLn = ldL(hs); }
    if (!atR) { float2 q = ldR(hs - 2); tRp_x = q.x; tRc = ldR(hs - 1); tRn = ldR(hs); }

    float4 ap, ac, an, mC, mN, mdum;
    float aLp, aLc, aLn, aRp, aRc, aRn;
    advrow(hs - 1, ap, aLp, aRp, mdum);
    roll(hs + 1);
    advrow(hs, ac, aLc, aRc, mC);

    #pragma unroll
    for (int i = 0; i < STRIP; ++i) {
        const int go = hs + i;
        roll(go + 2);
        advrow(go + 1, an, aLn, aRn, mN);
        if (go < H) {
            float4 v;
            v.x = ap.x + 2.f * ac.x + an.x;
            v.y = ap.y + 2.f * ac.y + an.y;
            v.z = ap.z + 2.f * ac.z + an.z;
            v.w = ap.w + 2.f * ac.w + an.w;
            float vL  = aLp + 2.f * aLc + aLn;
            float vR  = aRp + 2.f * aRc + aRn;
            float vLw = __shfl_up(v.w, 1);
            float vRx = __shfl_down(v.x, 1);
            if (isL) vLw = atL ? 0.f : vL;
            if (isR) vRx = atR ? 0.f : vR;
            float4 o;
            o.x = (vLw + 2.f * v.x + v.y) * 0.0625f * mC.x;
            o.y = (v.x + 2.f * v.y + v.z) * 0.0625f * mC.y;
            o.z = (v.y + 2.f * v.z + v.w) * 0.0625f * mC.z;
            o.w = (v.z + 2.f * v.w + vRx) * 0.0625f * mC.w;
            *(float4*)(To + (size_t)go * W + gw) = o;
        }
        ap = ac; ac = an;
        aLp = aLc; aLc = aLn; aRp = aRc; aRc = aRn;
        mC = mN;
    }
}

// ---------- generic fallback (round-1 LDS tile kernel, validated) ----------
constexpr int FTW = 64, FTH = 32;
constexpr int FSTW = FTW + 4, FSTH = FTH + 4;
constexpr int FMTW = FTW + 2, FMTH = FTH + 2;

__global__ __launch_bounds__(256)
void step_tile(const float* __restrict__ Tin, const float* __restrict__ ug,
               const float* __restrict__ vg, const float* __restrict__ mask,
               const float* __restrict__ coef, float* __restrict__ Tout,
               int H, int W) {
    __shared__ float sT[FSTH][FSTW];
    __shared__ float sM[FMTH][FMTW];
    const int tid = threadIdx.x;
    const int w0 = blockIdx.x * FTW;
    const int h0 = blockIdx.y * FTH;
    const int b  = blockIdx.z;
    const long plane = (long)H * W;
    const float* Tb  = Tin + b * plane;
    const float* ugb = ug  + b * plane;
    const float* vgb = vg  + b * plane;
    const float inv_dy = coef[H];

    for (int i = tid; i < FSTH * FSTW; i += NT) {
        int r = i / FSTW, c = i - r * FSTW;
        int gh = min(max(h0 - 2 + r, 0), H - 1);
        int gw = min(max(w0 - 2 + c, 0), W - 1);
        sT[r][c] = Tb[gh * W + gw];
    }
    __syncthreads();
    for (int i = tid; i < FMTH * FMTW; i += NT) {
        int r = i / FMTW, c = i - r * FMTW;
        int gh = h0 - 1 + r, gw = w0 - 1 + c;
        float v = 0.0f;
        if (gh >= 0 && gh < H && gw >= 0 && gw < W) {
            int sr = r + 1, sc = c + 1;
            float ndy = sT[sr + 1][sc] - sT[sr - 1][sc];
            float ndx = sT[sr][sc + 1] - sT[sr][sc - 1];
            float sy  = (gh == 0 || gh == H - 1) ? inv_dy : 0.5f * inv_dy;
            float ix  = coef[gh];
            float sx  = (gw == 0 || gw == W - 1) ? ix : 0.5f * ix;
            int   gi  = gh * W + gw;
            float F   = -(ugb[gi] * (ndx * sx) + vgb[gi] * (ndy * sy)) * mask[gi];
            v = sT[sr][sc] + DT_S * F;
        }
        sM[r][c] = v;
    }
    __syncthreads();
    float* To = Tout + b * plane;
    for (int i = tid; i < FTH * FTW; i += NT) {
        int r = i >> 6, c = i & (FTW - 1);
        int gh = h0 + r, gw = w0 + c;
        if (gh < H && gw < W) {
            int sr = r + 1, sc = c + 1;
            float s = (sM[sr-1][sc-1] + sM[sr-1][sc+1] + sM[sr+1][sc-1] + sM[sr+1][sc+1])
                    + 2.0f * (sM[sr-1][sc] + sM[sr+1][sc] + sM[sr][sc-1] + sM[sr][sc+1])
                    + 4.0f * sM[sr][sc];
            To[gh * W + gw] = s * 0.0625f * mask[gh * W + gw];
        }
    }
}

extern "C" void kernel_launch(void* const* d_in, const int* in_sizes, int n_in,
                              void* d_out, int out_size, void* d_ws, size_t ws_size,
                              hipStream_t stream) {
    const float* T0   = (const float*)d_in[0];
    const float* ug   = (const float*)d_in[1];
    const float* vg   = (const float*)d_in[2];
    const float* lat  = (const float*)d_in[3];
    const float* lon  = (const float*)d_in[4];
    const float* mask = (const float*)d_in[5];

    const int H = in_sizes[3];
    const int W = in_sizes[4];
    const int B = in_sizes[0] / (H * W);

    float* out  = (float*)d_out;
    float* ping = (float*)d_ws;                 // B*H*W floats
    float* coef = ping + (size_t)B * H * W;     // H+1 floats: 1/dx[h], then 1/dy

    prep_kernel<<<dim3((H + NT - 1) / NT), dim3(NT), 0, stream>>>(lat, lon, coef, H);

    const int STEPS = 48;

    if (W == FWAVES * 256) {
        // fused 2-step path: 24 launches, each = 2 simulated steps
        dim3 gridF2((H + SH2 - 1) / SH2, B);
        for (int i = 0; i < STEPS / 2; ++i) {
            const float* src = (i == 0) ? T0 : ((i & 1) ? ping : out);
            float*       dst = (i & 1) ? out : ping;
            fused2_kernel<<<gridF2, dim3(NT), 0, stream>>>(src, ug, vg, mask, coef, dst, H, W);
        }
    } else {
        const bool fast = (W % WPW) == 0;
        dim3 gridS(W / (fast ? WPW : 1), (H + 4 * STRIP - 1) / (4 * STRIP), B);
        dim3 gridF((W + FTW - 1) / FTW, (H + FTH - 1) / FTH, B);
        for (int i = 0; i < STEPS; ++i) {
            const float* src = (i == 0) ? T0 : ((i & 1) ? ping : out);
            float*       dst = (i & 1) ? out : ping;
            if (fast)
                stream_kernel<<<gridS, dim3(NT), 0, stream>>>(src, ug, vg, mask, coef, dst, H, W);
            else
                step_tile<<<gridF, dim3(NT), 0, stream>>>(src, ug, vg, mask, coef, dst, H, W);
        }
    }
}

// Round 2
// 1227.258 us; speedup vs baseline: 1.0420x; 1.0420x over previous
//
#include <hip/hip_runtime.h>

// Ocean advection + 3x3 binomial smoothing, 48 steps, fp32.
//
// Temporal fusion x2 (two advect+smooth steps per kernel, intermediate in
// registers) + ROUND-2 CHANGE: replace __syncthreads() with
//   s_waitcnt lgkmcnt(0) + raw s_barrier
// so the 9 per-row prefetch global loads stay IN FLIGHT across the barrier
// (hipcc's __syncthreads emits s_waitcnt vmcnt(0) which drained the entire
// prefetch queue every row -> latency-bound at 3 TB/s / 23% VALUBusy).
// Cross-barrier dependencies are ONLY the LDS edge-ring writes -> lgkmcnt(0)
// suffices for visibility; race distances (>=1 barrier) unchanged.
//
// fused2_kernel structure:
//   - one 256-thread block (4 waves) spans the FULL width W=1024
//     (wave wv owns cols [wv*256, wv*256+256), one float4 per lane)
//   - block streams down a 16-row chunk; 4-stage register pipeline skewed
//     2 rows/stage:   A1 = advect(T), S1 = smooth(A1), A2 = advect(S1),
//     out = smooth(A2).
//   - x-neighbors inside a wave via __shfl; across wave boundaries via tiny
//     LDS "edge rings" (8-row ring x 4 waves x {first,last} col). The 2-row
//     skew makes every cross-wave edge read >=1 barrier old -> ONE barrier
//     per row, race-free (slot distances 1..3 mod 8).
//   - all 9 global loads per row prefetched one iteration ahead.

#define DEG2RAD 0.017453292519943295f
#define R_EARTH 6371000.0f
#define DT_S 600.0f

constexpr int NT    = 256;   // threads per block
constexpr int STRIP = 8;     // legacy stream kernel: rows per wave
constexpr int WPW   = 256;   // legacy stream kernel: cols per wave

__global__ __launch_bounds__(256)
void prep_kernel(const float* __restrict__ lat, const float* __restrict__ lon,
                 float* __restrict__ coef, int H) {
    int h = blockIdx.x * blockDim.x + threadIdx.x;
    if (h < H) {
        float dlon = lon[1] - lon[0];
        coef[h] = 1.0f / (R_EARTH * DEG2RAD * dlon * cosf(lat[h] * DEG2RAD));
    }
    if (h == 0) {
        float dlat = lat[1] - lat[0];
        coef[H] = 1.0f / (R_EARTH * DEG2RAD * dlat);
    }
}

// ------------------------- fused 2-step kernel -----------------------------
constexpr int FWAVES = 4;    // waves per block, FWAVES*256 must == W
constexpr int SH2    = 16;   // output rows per block chunk

__global__ __launch_bounds__(256, 2)
void fused2_kernel(const float* __restrict__ Tin, const float* __restrict__ ug,
                   const float* __restrict__ vg, const float* __restrict__ mask,
                   const float* __restrict__ coef, float* __restrict__ Tout,
                   int H, int W) {
    const int lane = threadIdx.x & 63;
    const int wv   = threadIdx.x >> 6;
    const int h0   = blockIdx.x * SH2;
    const int b    = blockIdx.y;
    const int gw   = (wv << 8) + (lane << 2);
    const size_t plane = (size_t)H * W;
    const float* __restrict__ Tb  = Tin + b * plane;
    const float* __restrict__ ugb = ug  + b * plane;
    const float* __restrict__ vgb = vg  + b * plane;
    float* __restrict__ To = Tout + b * plane;
    const float inv_dy = coef[H];
    const bool isL = (lane == 0), isR = (lane == 63);
    const bool domL = (wv == 0), domR = (wv == FWAVES - 1);

    // edge rings: [row & 7][wave][0 = value at first col, 1 = value at last col]
    __shared__ float eT [8][FWAVES][2];
    __shared__ float eA1[8][FWAVES][2];
    __shared__ float eS1[8][FWAVES][2];
    __shared__ float eA2[8][FWAVES][2];

    auto rowc = [&](int r) { return min(max(r, 0), H - 1); };
    auto ld4 = [&](const float* __restrict__ p, int r) -> float4 {
        return *(const float4*)(p + (size_t)rowc(r) * W + gw);
    };

    const float4 z4 = make_float4(0.f, 0.f, 0.f, 0.f);
    // T chain: during body of iter j (tau = h0-4+j): t0..t2 = rows tau-3..tau-1
    float4 t0 = z4, t1 = z4, t2 = z4, t3 = z4;
    // stage output chains: during body = rows (stage_row-1 .. stage_row+1)
    float4 a1p = z4, a1c = z4, a1n = z4;     // A1 rows s-1, s, s+1  (s = tau-4)
    float4 s1p = z4, s1c = z4, s1n = z4;     // S1 rows q-1, q, q+1  (q = tau-6)
    float4 a2p = z4, a2c = z4, a2n = z4;     // A2 rows r-1, r, r+1  (r = tau-8)
    // one-iteration-ahead prefetch registers
    float4 uA_pf = z4, gA_pf = z4, mA_pf = z4;   // rows a+1 (A1 inputs)
    float4 uQ_pf = z4, gQ_pf = z4, mQ_pf = z4;   // rows q+1 (A2 inputs)
    float4 mS_pf = z4, mR_pf = z4;               // mask rows s+1, r+1

    #pragma unroll 4
    for (int j = 0; j < SH2 + 12; ++j) {
        const int tau = h0 - 4 + j;
        const int a = tau - 2, s = tau - 4, q = tau - 6, r = tau - 8;

        // ---- consume prefetches, roll T, issue next-iteration loads ----
        float4 uA = uA_pf, gA = gA_pf, mA = mA_pf;
        float4 uQ = uQ_pf, gQ = gQ_pf, mQ = mQ_pf;
        float4 mS = mS_pf, mR = mR_pf;
        t0 = t1; t1 = t2; t2 = t3;
        t3 = ld4(Tb, tau);
        uA_pf = ld4(ugb, a + 1); gA_pf = ld4(vgb, a + 1); mA_pf = ld4(mask, a + 1);
        uQ_pf = ld4(ugb, q + 1); gQ_pf = ld4(vgb, q + 1); mQ_pf = ld4(mask, q + 1);
        mS_pf = ld4(mask, s + 1); mR_pf = ld4(mask, r + 1);

        // publish T edges (row tau-1 = t2, loaded last iteration)
        if (isL) eT[(tau - 1) & 7][wv][0] = t2.x;
        if (isR) eT[(tau - 1) & 7][wv][1] = t2.w;

        // ---------------- stage A1: advect T, row a = tau-2 ----------------
        float4 a1_new = z4;
        if (a >= h0 - 3 && a <= h0 + SH2 + 2) {
            if (a >= 0 && a < H) {
                const float ix  = coef[a];
                const float sy  = (a == 0 || a == H - 1) ? inv_dy : 0.5f * inv_dy;
                const float sxh = 0.5f * ix;
                float cL = __shfl_up(t1.w, 1);
                float cR = __shfl_down(t1.x, 1);
                float sxx = sxh, sxw = sxh;
                if (isL) { if (domL) { cL = t1.x; sxx = ix; } else cL = eT[a & 7][wv - 1][1]; }
                if (isR) { if (domR) { cR = t1.w; sxw = ix; } else cR = eT[a & 7][wv + 1][0]; }
                a1_new.x = t1.x + DT_S * (-(uA.x * ((t1.y - cL) * sxx) + gA.x * ((t2.x - t0.x) * sy)) * mA.x);
                a1_new.y = t1.y + DT_S * (-(uA.y * ((t1.z - t1.x) * sxh) + gA.y * ((t2.y - t0.y) * sy)) * mA.y);
                a1_new.z = t1.z + DT_S * (-(uA.z * ((t1.w - t1.y) * sxh) + gA.z * ((t2.z - t0.z) * sy)) * mA.z);
                a1_new.w = t1.w + DT_S * (-(uA.w * ((cR - t1.z) * sxw) + gA.w * ((t2.w - t0.w) * sy)) * mA.w);
            }
            if (isL) eA1[a & 7][wv][0] = a1_new.x;
            if (isR) eA1[a & 7][wv][1] = a1_new.w;
        }

        // ---------------- stage S1: smooth A1, row s = tau-4 ----------------
        float4 s1_new = z4;
        if (s >= h0 - 2 && s <= h0 + SH2 + 1) {
            if (s >= 0 && s < H) {
                float4 v;
                v.x = a1p.x + 2.f * a1c.x + a1n.x;
                v.y = a1p.y + 2.f * a1c.y + a1n.y;
                v.z = a1p.z + 2.f * a1c.z + a1n.z;
                v.w = a1p.w + 2.f * a1c.w + a1n.w;
                float vL = __shfl_up(v.w, 1);
                float vR = __shfl_down(v.x, 1);
                if (isL) vL = domL ? 0.f
                    : (eA1[(s - 1) & 7][wv - 1][1] + 2.f * eA1[s & 7][wv - 1][1] + eA1[(s + 1) & 7][wv - 1][1]);
                if (isR) vR = domR ? 0.f
                    : (eA1[(s - 1) & 7][wv + 1][0] + 2.f * eA1[s & 7][wv + 1][0] + eA1[(s + 1) & 7][wv + 1][0]);
                s1_new.x = (vL  + 2.f * v.x + v.y) * 0.0625f * mS.x;
                s1_new.y = (v.x + 2.f * v.y + v.z) * 0.0625f * mS.y;
                s1_new.z = (v.y + 2.f * v.z + v.w) * 0.0625f * mS.z;
                s1_new.w = (v.z + 2.f * v.w + vR ) * 0.0625f * mS.w;
            }
            if (isL) eS1[s & 7][wv][0] = s1_new.x;
            if (isR) eS1[s & 7][wv][1] = s1_new.w;
        }

        // ---------------- stage A2: advect S1, row q = tau-6 ----------------
        float4 a2_new = z4;
        if (q >= h0 - 1 && q <= h0 + SH2) {
            if (q >= 0 && q < H) {
                const float ix  = coef[q];
                const float sxh = 0.5f * ix;
                float cL = __shfl_up(s1c.w, 1);
                float cR = __shfl_down(s1c.x, 1);
                float sxx = sxh, sxw = sxh;
                if (isL) { if (domL) { cL = s1c.x; sxx = ix; } else cL = eS1[q & 7][wv - 1][1]; }
                if (isR) { if (domR) { cR = s1c.w; sxw = ix; } else cR = eS1[q & 7][wv + 1][0]; }
                // y-derivative: one-sided at domain rows 0 / H-1 (S1 chain has
                // zeros outside the domain, so select operands explicitly)
                const float4 yl = (q == 0)     ? s1c : s1p;
                const float4 yh = (q == H - 1) ? s1c : s1n;
                const float sy  = (q == 0 || q == H - 1) ? inv_dy : 0.5f * inv_dy;
                a2_new.x = s1c.x + DT_S * (-(uQ.x * ((s1c.y - cL) * sxx) + gQ.x * ((yh.x - yl.x) * sy)) * mQ.x);
                a2_new.y = s1c.y + DT_S * (-(uQ.y * ((s1c.z - s1c.x) * sxh) + gQ.y * ((yh.y - yl.y) * sy)) * mQ.y);
                a2_new.z = s1c.z + DT_S * (-(uQ.z * ((s1c.w - s1c.y) * sxh) + gQ.z * ((yh.z - yl.z) * sy)) * mQ.z);
                a2_new.w = s1c.w + DT_S * (-(uQ.w * ((cR - s1c.z) * sxw) + gQ.w * ((yh.w - yl.w) * sy)) * mQ.w);
            }
            if (isL) eA2[q & 7][wv][0] = a2_new.x;
            if (isR) eA2[q & 7][wv][1] = a2_new.w;
        }

        // ---------------- stage out: smooth A2, row r = tau-8 ---------------
        if (r >= h0 && r < min(h0 + SH2, H)) {
            float4 v;
            v.x = a2p.x + 2.f * a2c.x + a2n.x;
            v.y = a2p.y + 2.f * a2c.y + a2n.y;
            v.z = a2p.z + 2.f * a2c.z + a2n.z;
            v.w = a2p.w + 2.f * a2c.w + a2n.w;
            float vL = __shfl_up(v.w, 1);
            float vR = __shfl_down(v.x, 1);
            if (isL) vL = domL ? 0.f
                : (eA2[(r - 1) & 7][wv - 1][1] + 2.f * eA2[r & 7][wv - 1][1] + eA2[(r + 1) & 7][wv - 1][1]);
            if (isR) vR = domR ? 0.f
                : (eA2[(r - 1) & 7][wv + 1][0] + 2.f * eA2[r & 7][wv + 1][0] + eA2[(r + 1) & 7][wv + 1][0]);
            float4 o;
            o.x = (vL  + 2.f * v.x + v.y) * 0.0625f * mR.x;
            o.y = (v.x + 2.f * v.y + v.z) * 0.0625f * mR.y;
            o.z = (v.y + 2.f * v.z + v.w) * 0.0625f * mR.z;
            o.w = (v.z + 2.f * v.w + vR ) * 0.0625f * mR.w;
            *(float4*)(To + (size_t)r * W + gw) = o;
        }

        // ---- roll stage chains ----
        a1p = a1c; a1c = a1n; a1n = a1_new;
        s1p = s1c; s1c = s1n; s1n = s1_new;
        a2p = a2c; a2c = a2n; a2n = a2_new;

        // ROUND-2: raw barrier. Only LDS edge publishes must be visible across
        // it -> drain lgkmcnt only; global prefetch loads stay IN FLIGHT
        // (__syncthreads would emit s_waitcnt vmcnt(0) and kill the pipeline).
        asm volatile("s_waitcnt lgkmcnt(0)" ::: "memory");
        __builtin_amdgcn_s_barrier();
    }
}

// --------- legacy single-step stream kernel (fallback, W % 256 == 0) -------
__global__ __launch_bounds__(256, 4)
void stream_kernel(const float* __restrict__ Tin, const float* __restrict__ ug,
                   const float* __restrict__ vg, const float* __restrict__ mask,
                   const float* __restrict__ coef, float* __restrict__ Tout,
                   int H, int W) {
    const int lane = threadIdx.x & 63;
    const int wv   = threadIdx.x >> 6;
    const int ws   = blockIdx.x * WPW;
    const int hs   = (blockIdx.y * 4 + wv) * STRIP;
    const int b    = blockIdx.z;
    if (hs >= H) return;
    const size_t plane = (size_t)H * W;
    const float* __restrict__ Tb  = Tin + b * plane;
    const float* __restrict__ ugb = ug  + b * plane;
    const float* __restrict__ vgb = vg  + b * plane;
    float* __restrict__ To = Tout + b * plane;
    const float inv_dy = coef[H];
    const bool atL = (ws == 0);
    const bool atR = (ws + WPW >= W);
    const bool isL = (lane == 0);
    const bool isR = (lane == 63);
    const int gw = ws + 4 * lane;

    auto clampr = [&](int r) { return min(max(r, 0), H - 1); };
    auto ldT = [&](int r) -> float4 {
        return *(const float4*)(Tb + (size_t)clampr(r) * W + gw);
    };
    auto ldL = [&](int r) -> float2 {
        float4 q = *(const float4*)(Tb + (size_t)clampr(r) * W + (ws - 4));
        return make_float2(q.z, q.w);
    };
    auto ldR = [&](int r) -> float2 {
        float4 q = *(const float4*)(Tb + (size_t)clampr(r) * W + (ws + WPW));
        return make_float2(q.x, q.y);
    };

    float4 tp, tc, tn;
    float  tLp_w = 0.f; float2 tLc = make_float2(0.f, 0.f), tLn = make_float2(0.f, 0.f);
    float  tRp_x = 0.f; float2 tRc = make_float2(0.f, 0.f), tRn = make_float2(0.f, 0.f);

    auto roll = [&](int rnext) {
        tp = tc; tc = tn; tn = ldT(rnext);
        if (!atL) { tLp_w = tLc.y; tLc = tLn; tLn = ldL(rnext); }
        if (!atR) { tRp_x = tRc.x; tRc = tRn; tRn = ldR(rnext); }
    };

    auto advrow = [&](int r, float4& a, float& aL, float& aR, float4& mOut) {
        if (r < 0 || r >= H) {
            a = make_float4(0.f, 0.f, 0.f, 0.f); aL = 0.f; aR = 0.f;
            mOut = make_float4(0.f, 0.f, 0.f, 0.f); return;
        }
        const size_t ro = (size_t)r * W;
        const float ix  = coef[r];
        const float sy  = (r == 0 || r == H - 1) ? inv_dy : 0.5f * inv_dy;
        const float sxh = 0.5f * ix;
        float4 u4 = *(const float4*)(ugb + ro + gw);
        float4 g4 = *(const float4*)(vgb + ro + gw);
        float4 m4 = *(const float4*)(mask + ro + gw);
        float cLw = __shfl_up(tc.w, 1);
        float cRx = __shfl_down(tc.x, 1);
        float sxx = sxh, sxw = sxh;
        if (isL) { if (atL) { cLw = tc.x; sxx = ix; } else { cLw = tLc.y; } }
        if (isR) { if (atR) { cRx = tc.w; sxw = ix; } else { cRx = tRc.x; } }
        a.x = tc.x + DT_S * (-(u4.x * ((tc.y - cLw) * sxx) + g4.x * ((tn.x - tp.x) * sy)) * m4.x);
        a.y = tc.y + DT_S * (-(u4.y * ((tc.z - tc.x) * sxh) + g4.y * ((tn.y - tp.y) * sy)) * m4.y);
        a.z = tc.z + DT_S * (-(u4.z * ((tc.w - tc.y) * sxh) + g4.z * ((tn.z - tp.z) * sy)) * m4.z);
        a.w = tc.w + DT_S * (-(u4.w * ((cRx - tc.z) * sxw) + g4.w * ((tn.w - tp.w) * sy)) * m4.w);
        if (!atL) {
            float uL = ((const float4*)(ugb + ro + (ws - 4)))->w;
            float gL = ((const float4*)(vgb + ro + (ws - 4)))->w;
            float mL = ((const float4*)(mask + ro + (ws - 4)))->w;
            aL = tLc.y + DT_S * (-(uL * ((tc.x - tLc.x) * sxh) + gL * ((tLn.y - tLp_w) * sy)) * mL);
        } else aL = 0.f;
        if (!atR) {
            float uR = ((const float4*)(ugb + ro + (ws + WPW)))->x;
            float gR = ((const float4*)(vgb + ro + (ws + WPW)))->x;
            float mR = ((const float4*)(mask + ro + (ws + WPW)))->x;
            aR = tRc.x + DT_S * (-(uR * ((tRc.y - tc.w) * sxh) + gR * ((tRn.x - tRp_x) * sy)) * mR);
        } else aR = 0.f;
        mOut = m4;
    };

    tp = ldT(hs - 2); tc = ldT(hs - 1); tn = ldT(hs);
    if (!atL) { float2 q = ldL(hs - 2); tLp_w = q.y; tLc = ldL(hs - 1); tLn = ldL(hs); }
    if (!atR) { float2 q = ldR(hs - 2); tRp_x = q.x; tRc = ldR(hs - 1); tRn = ldR(hs); }

    float4 ap, ac, an, mC, mN, mdum;
    float aLp, aLc, aLn, aRp, aRc, aRn;
    advrow(hs - 1, ap, aLp, aRp, mdum);
    roll(hs + 1);
    advrow(hs, ac, aLc, aRc, mC);

    #pragma unroll
    for (int i = 0; i < STRIP; ++i) {
        const int go = hs + i;
        roll(go + 2);
        advrow(go + 1, an, aLn, aRn, mN);
        if (go < H) {
            float4 v;
            v.x = ap.x + 2.f * ac.x + an.x;
            v.y = ap.y + 2.f * ac.y + an.y;
            v.z = ap.z + 2.f * ac.z + an.z;
            v.w = ap.w + 2.f * ac.w + an.w;
            float vL  = aLp + 2.f * aLc + aLn;
            float vR  = aRp + 2.f * aRc + aRn;
            float vLw = __shfl_up(v.w, 1);
            float vRx = __shfl_down(v.x, 1);
            if (isL) vLw = atL ? 0.f : vL;
            if (isR) vRx = atR ? 0.f : vR;
            float4 o;
            o.x = (vLw + 2.f * v.x + v.y) * 0.0625f * mC.x;
            o.y = (v.x + 2.f * v.y + v.z) * 0.0625f * mC.y;
            o.z = (v.y + 2.f * v.z + v.w) * 0.0625f * mC.z;
            o.w = (v.z + 2.f * v.w + vRx) * 0.0625f * mC.w;
            *(float4*)(To + (size_t)go * W + gw) = o;
        }
        ap = ac; ac = an;
        aLp = aLc; aLc = aLn; aRp = aRc; aRc = aRn;
        mC = mN;
    }
}

// ---------- generic fallback (round-1 LDS tile kernel, validated) ----------
constexpr int FTW = 64, FTH = 32;
constexpr int FSTW = FTW + 4, FSTH = FTH + 4;
constexpr int FMTW = FTW + 2, FMTH = FTH + 2;

__global__ __launch_bounds__(256)
void step_tile(const float* __restrict__ Tin, const float* __restrict__ ug,
               const float* __restrict__ vg, const float* __restrict__ mask,
               const float* __restrict__ coef, float* __restrict__ Tout,
               int H, int W) {
    __shared__ float sT[FSTH][FSTW];
    __shared__ float sM[FMTH][FMTW];
    const int tid = threadIdx.x;
    const int w0 = blockIdx.x * FTW;
    const int h0 = blockIdx.y * FTH;
    const int b  = blockIdx.z;
    const long plane = (long)H * W;
    const float* Tb  = Tin + b * plane;
    const float* ugb = ug  + b * plane;
    const float* vgb = vg  + b * plane;
    const float inv_dy = coef[H];

    for (int i = tid; i < FSTH * FSTW; i += NT) {
        int r = i / FSTW, c = i - r * FSTW;
        int gh = min(max(h0 - 2 + r, 0), H - 1);
        int gw = min(max(w0 - 2 + c, 0), W - 1);
        sT[r][c] = Tb[gh * W + gw];
    }
    __syncthreads();
    for (int i = tid; i < FMTH * FMTW; i += NT) {
        int r = i / FMTW, c = i - r * FMTW;
        int gh = h0 - 1 + r, gw = w0 - 1 + c;
        float v = 0.0f;
        if (gh >= 0 && gh < H && gw >= 0 && gw < W) {
            int sr = r + 1, sc = c + 1;
            float ndy = sT[sr + 1][sc] - sT[sr - 1][sc];
            float ndx = sT[sr][sc + 1] - sT[sr][sc - 1];
            float sy  = (gh == 0 || gh == H - 1) ? inv_dy : 0.5f * inv_dy;
            float ix  = coef[gh];
            float sx  = (gw == 0 || gw == W - 1) ? ix : 0.5f * ix;
            int   gi  = gh * W + gw;
            float F   = -(ugb[gi] * (ndx * sx) + vgb[gi] * (ndy * sy)) * mask[gi];
            v = sT[sr][sc] + DT_S * F;
        }
        sM[r][c] = v;
    }
    __syncthreads();
    float* To = Tout + b * plane;
    for (int i = tid; i < FTH * FTW; i += NT) {
        int r = i >> 6, c = i & (FTW - 1);
        int gh = h0 + r, gw = w0 + c;
        if (gh < H && gw < W) {
            int sr = r + 1, sc = c + 1;
            float s = (sM[sr-1][sc-1] + sM[sr-1][sc+1] + sM[sr+1][sc-1] + sM[sr+1][sc+1])
                    + 2.0f * (sM[sr-1][sc] + sM[sr+1][sc] + sM[sr][sc-1] + sM[sr][sc+1])
                    + 4.0f * sM[sr][sc];
            To[gh * W + gw] = s * 0.0625f * mask[gh * W + gw];
        }
    }
}

extern "C" void kernel_launch(void* const* d_in, const int* in_sizes, int n_in,
                              void* d_out, int out_size, void* d_ws, size_t ws_size,
                              hipStream_t stream) {
    const float* T0   = (const float*)d_in[0];
    const float* ug   = (const float*)d_in[1];
    const float* vg   = (const float*)d_in[2];
    const float* lat  = (const float*)d_in[3];
    const float* lon  = (const float*)d_in[4];
    const float* mask = (const float*)d_in[5];

    const int H = in_sizes[3];
    const int W = in_sizes[4];
    const int B = in_sizes[0] / (H * W);

    float* out  = (float*)d_out;
    float* ping = (float*)d_ws;                 // B*H*W floats
    float* coef = ping + (size_t)B * H * W;     // H+1 floats: 1/dx[h], then 1/dy

    prep_kernel<<<dim3((H + NT - 1) / NT), dim3(NT), 0, stream>>>(lat, lon, coef, H);

    const int STEPS = 48;

    if (W == FWAVES * 256) {
        // fused 2-step path: 24 launches, each = 2 simulated steps
        dim3 gridF2((H + SH2 - 1) / SH2, B);
        for (int i = 0; i < STEPS / 2; ++i) {
            const float* src = (i == 0) ? T0 : ((i & 1) ? ping : out);
            float*       dst = (i & 1) ? out : ping;
            fused2_kernel<<<gridF2, dim3(NT), 0, stream>>>(src, ug, vg, mask, coef, dst, H, W);
        }
    } else {
        const bool fast = (W % WPW) == 0;
        dim3 gridS(W / (fast ? WPW : 1), (H + 4 * STRIP - 1) / (4 * STRIP), B);
        dim3 gridF((W + FTW - 1) / FTW, (H + FTH - 1) / FTH, B);
        for (int i = 0; i < STEPS; ++i) {
            const float* src = (i == 0) ? T0 : ((i & 1) ? ping : out);
            float*       dst = (i & 1) ? out : ping;
            if (fast)
                stream_kernel<<<gridS, dim3(NT), 0, stream>>>(src, ug, vg, mask, coef, dst, H, W);
            else
                step_tile<<<gridF, dim3(NT), 0, stream>>>(src, ug, vg, mask, coef, dst, H, W);
        }
    }
}